// Round 6
// baseline (6423.149 us; speedup 1.0000x reference)
//
#include <hip/hip_runtime.h>
#include <hip/hip_bf16.h>

// ---------------------------------------------------------------------------
// Bidirectional 2-layer LSTM (B=128, T=512, H=256, INPUT=4) + mean-pool + FC.
//
// Round-6: data-embedded presence (LSB sentinel) -> no flags, no drains.
//  - Producers force the LSB of every stored bf16 to a known bit, fire
//    relaxed AGENT atomic stores (write-through to MALL), and continue.
//  - Consumers masked-re-poll their own data chunks until all LSBs match.
//    h0: full ring, LSB always 1 (slot0 init = 0x0001 denormals ~= 0).
//    h1: parity-2 ring, expected LSB alternates per slot generation
//        ((m>>1)&1); init slot0 = 0x0000 (gen-0 zeros), slot1 = 0x0001.
//  - Overwrite safety: a block enters step s only after observing ALL peer
//    blocks' s-1 data => those blocks consumed s-2 => parity reuse is safe.
//  - k_l1: h0 b128 loads issued BEFORE the h1 poll (latency hides under the
//    wait); no LDS staging; gate-exchange LDS double-buffered (1 barrier).
// ---------------------------------------------------------------------------

typedef __bf16 bf16;
typedef __bf16 bf16x8 __attribute__((ext_vector_type(8)));
typedef float  f32x4  __attribute__((ext_vector_type(4)));
typedef unsigned short u16;
typedef unsigned int u32;
typedef unsigned long long u64;
typedef u64 u64x2 __attribute__((ext_vector_type(2)));

#define T_SEQ 512
#define BATCH 128
#define HID   256

// ws layout (bytes)
#define H0_BYTES   67239936ULL                  // bf16 [2][513][128][256]
#define H1_OFF     H0_BYTES                     // bf16 [2][2][128][256] parity
#define POOL_OFF   (H1_OFF + 262144ULL)         // f32  [2][128][256]

#define LSBM 0x0001000100010001ULL

#define MFMA16(a, b, c) __builtin_amdgcn_mfma_f32_16x16x32_bf16((a), (b), (c), 0, 0, 0)
#define AL(p)     __hip_atomic_load((p), __ATOMIC_RELAXED, __HIP_MEMORY_SCOPE_AGENT)
#define AS(p, v)  __hip_atomic_store((p), (v), __ATOMIC_RELAXED, __HIP_MEMORY_SCOPE_AGENT)

__device__ __forceinline__ float fsig(float v) {
    return __builtin_amdgcn_rcpf(1.0f + __expf(-v));
}
__device__ __forceinline__ float ftanh(float v) {
    float a = fabsf(v);
    float e = __expf(-2.0f * a);
    float r = (1.0f - e) * __builtin_amdgcn_rcpf(1.0f + e);
    return v < 0.0f ? -r : r;
}
__device__ __forceinline__ bf16x8 mk_a(u64 lo, u64 hi) {
    u64x2 t; t[0] = lo; t[1] = hi;
    return __builtin_bit_cast(bf16x8, t);
}

// ---------------------------------------------------------------------------
__global__ void k_init(unsigned int* ws_u) {
    const int t = blockIdx.x * 256 + threadIdx.x;       // 0..16383
    // h0 slot0, both dirs: present (LSB=1), value ~ denormal zero
    ws_u[t] = 0x00010001u;
    ws_u[(size_t)513 * 16384 + t] = 0x00010001u;
    // h1 parity ring: [dir][slot] 16384 u32 each
    unsigned int* h1u = ws_u + (H1_OFF / 4);
    h1u[t]         = 0u;            // dir0 slot0: gen-0 zeros (LSB=0)
    h1u[16384 + t] = 0x00010001u;   // dir0 slot1: absent marker (LSB=1)
    h1u[32768 + t] = 0u;            // dir1 slot0
    h1u[49152 + t] = 0x00010001u;   // dir1 slot1
}

// ---------------------------------------------------------------------------
// Layer 0: grid 64 = dir(2) x batch-half(2) x gate-group(16). 256 thr/block.
// M=64 rows (waves split M by 16), N=64 cols (i,f,g,o of 16 hidden units),
// K=256. Weights: 4x8 B-fragments = 128 VGPRs, loaded once. No barriers,
// no flags: consumers poll the data LSBs directly.
// ---------------------------------------------------------------------------
__global__ __launch_bounds__(256, 1) void k_l0(
    const float* __restrict__ x, const float* __restrict__ wih,
    const float* __restrict__ whh, const float* __restrict__ bih,
    const float* __restrict__ bhh, bf16* __restrict__ h0)
{
    __shared__ __align__(16) u16 Hs[4][16][24];        // per-wave repack

    const int blk = blockIdx.x;
    const int dir = blk >> 5, bh = (blk >> 4) & 1, g = blk & 15;
    const int tid = threadIdx.x, wave = tid >> 6, lane = tid & 63;
    const int l15 = lane & 15, q = lane >> 4;
    const int j = g * 16 + l15;                 // hidden unit (column)

    // B fragments: Bf[gate][kt], n = gate*256 + j, k = kt*32 + q*8 .. +8
    bf16x8 Bf[4][8];
#pragma unroll
    for (int tg = 0; tg < 4; ++tg) {
        const float* wr = whh + ((size_t)(dir * 1024 + tg * 256 + j)) * 256 + q * 8;
#pragma unroll
        for (int kt = 0; kt < 8; ++kt) {
            f32x4 aa = *(const f32x4*)(wr + kt * 32);
            f32x4 bb = *(const f32x4*)(wr + kt * 32 + 4);
            bf16x8 f;
            f[0] = (bf16)aa[0]; f[1] = (bf16)aa[1]; f[2] = (bf16)aa[2]; f[3] = (bf16)aa[3];
            f[4] = (bf16)bb[0]; f[5] = (bf16)bb[1]; f[6] = (bf16)bb[2]; f[7] = (bf16)bb[3];
            Bf[tg][kt] = f;
        }
    }
    float biasg[4], wx[4][4];
#pragma unroll
    for (int tg = 0; tg < 4; ++tg) {
        const int n = dir * 1024 + tg * 256 + j;
        biasg[tg] = bih[n] + bhh[n];
#pragma unroll
        for (int d2 = 0; d2 < 4; ++d2) wx[tg][d2] = wih[(size_t)n * 4 + d2];
    }

    float c4[4] = {0.f, 0.f, 0.f, 0.f};
    const int arow  = bh * 64 + wave * 16 + l15;   // A-operand row (load)
    const int mrow0 = bh * 64 + wave * 16 + q * 4; // C rows base (update)
    const int srow = lane >> 2, scg = (lane & 3) * 4;  // 8B-store mapping

#pragma unroll 1
    for (int s = 1; s <= T_SEQ; ++s) {
        const int t_in = dir ? (T_SEQ - s) : (s - 1);

        // --- bias + x(t).w_ih (non-racy, cached loads) ---
        f32x4 xv[4];
#pragma unroll
        for (int r = 0; r < 4; ++r)
            xv[r] = *(const f32x4*)(x + ((size_t)(mrow0 + r) * T_SEQ + t_in) * 4);
        f32x4 acc[4];
#pragma unroll
        for (int tg = 0; tg < 4; ++tg) {
#pragma unroll
            for (int r = 0; r < 4; ++r) {
                acc[tg][r] = biasg[tg] + xv[r][0] * wx[tg][0] + xv[r][1] * wx[tg][1]
                                       + xv[r][2] * wx[tg][2] + xv[r][3] * wx[tg][3];
            }
        }

        // --- data-poll A chunks (LSB==1 => present) ---
        const u64* hsrc = (const u64*)(h0 + ((size_t)(dir * 513 + (s - 1)) * BATCH + arow) * HID)
                          + q * 2;
        u64 av[16];
        {
            unsigned pend = 0xffffu;
            int rounds = 200000;
            do {
#pragma unroll
                for (int c = 0; c < 16; ++c)
                    if (pend & (1u << c)) av[c] = AL(hsrc + (c >> 1) * 8 + (c & 1));
                unsigned np = 0;
#pragma unroll
                for (int c = 0; c < 16; ++c)
                    if ((av[c] & LSBM) != LSBM) np |= (1u << c);
                pend = np;
            } while (pend && --rounds > 0);
        }
#pragma unroll
        for (int kt = 0; kt < 8; ++kt) {
            const bf16x8 A = mk_a(av[2 * kt], av[2 * kt + 1]);
            acc[0] = MFMA16(A, Bf[0][kt], acc[0]);
            acc[1] = MFMA16(A, Bf[1][kt], acc[1]);
            acc[2] = MFMA16(A, Bf[2][kt], acc[2]);
            acc[3] = MFMA16(A, Bf[3][kt], acc[3]);
        }

        // --- cell update -> per-wave LDS repack (LSB forced to 1) ---
#pragma unroll
        for (int r = 0; r < 4; ++r) {
            const float iv = fsig(acc[0][r]);
            const float fv = fsig(acc[1][r]);
            const float gv = ftanh(acc[2][r]);
            const float ov = fsig(acc[3][r]);
            c4[r] = fv * c4[r] + iv * gv;
            const float hv = ov * ftanh(c4[r]);
            const u16 hb = (u16)(__builtin_bit_cast(u16, (bf16)hv) | 1u);
            Hs[wave][q * 4 + r][l15] = hb;
        }
        asm volatile("s_waitcnt lgkmcnt(0)" ::: "memory");
        // 8B atomic store, fire-and-forget (no drain, no flag)
        {
            const u64 hv8 = *(const u64*)&Hs[wave][srow][scg];
            u64* dst = (u64*)(h0 + ((size_t)(dir * 513 + s) * BATCH
                              + bh * 64 + wave * 16 + srow) * HID + g * 16 + scg);
            AS(dst, hv8);
        }
    }
}

// ---------------------------------------------------------------------------
// Layer 1: grid 128 = dir(2) x batch-quarter(4) x gate-group(16).
// M=32 rows, N=64 cols (waves = gates), K=768 ([h1_prev|h0f|h0b]).
// h0 b128 loads issued first (latency hides under the h1 poll); h1 via
// per-wave atomic data-poll (alternating-LSB parity ring); gate exchange
// through double-buffered LDS (one barrier per step); per-thread 2B
// atomic h stores with forced LSB.
// ---------------------------------------------------------------------------
__global__ __launch_bounds__(256, 1) void k_l1(
    const float* __restrict__ wih1, const float* __restrict__ whh1,
    const float* __restrict__ bih1, const float* __restrict__ bhh1,
    bf16* __restrict__ h0, bf16* __restrict__ h1,
    float* __restrict__ pooled)
{
    __shared__ float Gs[2][4][32][17];                 // parity double-buffer

    const int blk = blockIdx.x;
    const int dir = blk >> 6, bq = (blk >> 4) & 3, g = blk & 15;
    const int tid = threadIdx.x, wave = tid >> 6, lane = tid & 63;
    const int l15 = lane & 15, q = lane >> 4;
    const int n = dir * 1024 + wave * 256 + g * 16 + l15;  // wave = gate

    // B fragments: 24 x 4 VGPR = 96 VGPRs. kt<8 -> Whh1; 8..15 -> h0f part
    // of Wih1; 16..23 -> h0b part.
    bf16x8 Bf[24];
#pragma unroll
    for (int kt = 0; kt < 24; ++kt) {
        const int k = kt * 32 + q * 8;
        const float* src = (kt < 8) ? (whh1 + (size_t)n * 256 + k)
                                    : (wih1 + (size_t)n * 512 + (k - 256));
        f32x4 aa = *(const f32x4*)src;
        f32x4 bb = *(const f32x4*)(src + 4);
        bf16x8 f;
        f[0] = (bf16)aa[0]; f[1] = (bf16)aa[1]; f[2] = (bf16)aa[2]; f[3] = (bf16)aa[3];
        f[4] = (bf16)bb[0]; f[5] = (bf16)bb[1]; f[6] = (bf16)bb[2]; f[7] = (bf16)bb[3];
        Bf[kt] = f;
    }
    const float biasw = bih1[n] + bhh1[n];
    const int r0 = tid >> 4, colu = tid & 15;     // update: rows r0, r0+16
    float cst[2] = {0.f, 0.f}, pool[2] = {0.f, 0.f};
    u16* h1u = (u16*)h1;

#pragma unroll 1
    for (int s = 1; s <= T_SEQ; ++s) {
        const int slotf = dir ? (513 - s) : s;     // h0 fwd slot for time t
        const int slotb = dir ? s : (513 - s);     // h0 bwd slot for time t
        const int pb = s & 1;

        // --- issue h0 loads first (plain, cached; resolve during poll) ---
        const bf16* f0 = h0 + ((size_t)slotf * BATCH + bq * 32 + l15) * HID + q * 8;
        const bf16* b0 = h0 + ((size_t)(513 + slotb) * BATCH + bq * 32 + l15) * HID + q * 8;
        bf16x8 af0[8], af1[8], ab0[8], ab1[8];
#pragma unroll
        for (int kt = 0; kt < 8; ++kt) {
            af0[kt] = *(const bf16x8*)(f0 + kt * 32);
            af1[kt] = *(const bf16x8*)(f0 + 16 * HID + kt * 32);
            ab0[kt] = *(const bf16x8*)(b0 + kt * 32);
            ab1[kt] = *(const bf16x8*)(b0 + 16 * HID + kt * 32);
        }

        // --- data-poll h1_prev (expected LSB = ((s-1)>>1)&1) ---
        const u64 want = (((s - 1) >> 1) & 1) ? LSBM : 0ULL;
        const u64* hp0 = (const u64*)(h1 + ((size_t)(dir * 2 + ((s - 1) & 1)) * BATCH
                                            + bq * 32 + l15) * HID) + q * 2;
        const u64* hp1 = hp0 + 16 * (HID / 4);
        u64 av[32];
        {
            u32 pend = 0xffffffffu;
            int rounds = 200000;
            do {
#pragma unroll
                for (int c = 0; c < 16; ++c)
                    if (pend & (1u << c)) av[c] = AL(hp0 + (c >> 1) * 8 + (c & 1));
#pragma unroll
                for (int c = 0; c < 16; ++c)
                    if (pend & (1u << (16 + c))) av[16 + c] = AL(hp1 + (c >> 1) * 8 + (c & 1));
                u32 np = 0;
#pragma unroll
                for (int c = 0; c < 32; ++c)
                    if ((av[c] & LSBM) != want) np |= (1u << c);
                pend = np;
            } while (pend && --rounds > 0);
        }

        // --- GEMM: h0 part (K=512) + recurrent part (K=256) ---
        f32x4 acc0 = {biasw, biasw, biasw, biasw};
        f32x4 acc1 = acc0;
#pragma unroll
        for (int kt = 0; kt < 8; ++kt) {
            acc0 = MFMA16(af0[kt], Bf[8 + kt], acc0);
            acc1 = MFMA16(af1[kt], Bf[8 + kt], acc1);
        }
#pragma unroll
        for (int kt = 0; kt < 8; ++kt) {
            acc0 = MFMA16(ab0[kt], Bf[16 + kt], acc0);
            acc1 = MFMA16(ab1[kt], Bf[16 + kt], acc1);
        }
#pragma unroll
        for (int kt = 0; kt < 8; ++kt) {
            acc0 = MFMA16(mk_a(av[2 * kt], av[2 * kt + 1]), Bf[kt], acc0);
            acc1 = MFMA16(mk_a(av[16 + 2 * kt], av[16 + 2 * kt + 1]), Bf[kt], acc1);
        }

        // --- gate exchange via double-buffered LDS (one barrier) ---
#pragma unroll
        for (int r = 0; r < 4; ++r) {
            Gs[pb][wave][q * 4 + r][l15]      = acc0[r];
            Gs[pb][wave][16 + q * 4 + r][l15] = acc1[r];
        }
        __syncthreads();

        // --- cell update: rows r0, r0+16 of hidden unit colu ---
        const u16 sbit = (u16)((s >> 1) & 1);
        u16* hdst = h1u + ((size_t)(dir * 2 + (s & 1)) * BATCH + bq * 32) * HID + g * 16 + colu;
#pragma unroll
        for (int rr = 0; rr < 2; ++rr) {
            const int r = r0 + rr * 16;
            const float iv = fsig(Gs[pb][0][r][colu]);
            const float fv = fsig(Gs[pb][1][r][colu]);
            const float gv = ftanh(Gs[pb][2][r][colu]);
            const float ov = fsig(Gs[pb][3][r][colu]);
            cst[rr] = fv * cst[rr] + iv * gv;
            const float hv = ov * ftanh(cst[rr]);
            pool[rr] += hv;                                // unforced for pooling
            u16 hb = __builtin_bit_cast(u16, (bf16)hv);
            hb = (u16)((hb & 0xFFFEu) | sbit);
            AS(hdst + (size_t)r * HID, hb);                // 2B fire-and-forget
        }
    }
    // mean pool epilogue
#pragma unroll
    for (int rr = 0; rr < 2; ++rr) {
        const int r = r0 + rr * 16;
        pooled[((size_t)dir * BATCH + bq * 32 + r) * HID + g * 16 + colu] =
            pool[rr] * (1.0f / 512.0f);
    }
}

// ---------------------------------------------------------------------------
__global__ void k_fc(const float* __restrict__ pooled, const float* __restrict__ fcw,
                     const float* __restrict__ fcb, float* __restrict__ out)
{
    const int b = blockIdx.x;            // 128 blocks, 64 threads
    const int lane = threadIdx.x;
    float s0 = 0.f, s1 = 0.f;
#pragma unroll
    for (int jj = 0; jj < 8; ++jj) {
        const int jx = lane + jj * 64;   // 0..511
        const float p = (jx < 256) ? pooled[(size_t)b * 256 + jx]
                                   : pooled[32768 + (size_t)b * 256 + (jx - 256)];
        s0 += p * fcw[jx];
        s1 += p * fcw[512 + jx];
    }
#pragma unroll
    for (int off = 32; off > 0; off >>= 1) {
        s0 += __shfl_down(s0, off);
        s1 += __shfl_down(s1, off);
    }
    if (lane == 0) {
        out[b * 2 + 0] = s0 + fcb[0];
        out[b * 2 + 1] = s1 + fcb[1];
    }
}

// ---------------------------------------------------------------------------
extern "C" void kernel_launch(void* const* d_in, const int* in_sizes, int n_in,
                              void* d_out, int out_size, void* d_ws, size_t ws_size,
                              hipStream_t stream)
{
    const float* x    = (const float*)d_in[0];
    const float* wih0 = (const float*)d_in[1];
    const float* whh0 = (const float*)d_in[2];
    const float* bih0 = (const float*)d_in[3];
    const float* bhh0 = (const float*)d_in[4];
    const float* wih1 = (const float*)d_in[5];
    const float* whh1 = (const float*)d_in[6];
    const float* bih1 = (const float*)d_in[7];
    const float* bhh1 = (const float*)d_in[8];
    const float* fcw  = (const float*)d_in[9];
    const float* fcb  = (const float*)d_in[10];
    float* out = (float*)d_out;

    char* ws = (char*)d_ws;
    bf16* h0      = (bf16*)ws;
    bf16* h1      = (bf16*)(ws + H1_OFF);
    float* pooled = (float*)(ws + POOL_OFF);

    k_init<<<dim3(64), dim3(256), 0, stream>>>((unsigned int*)ws);
    k_l0<<<dim3(64), dim3(256), 0, stream>>>(x, wih0, whh0, bih0, bhh0, h0);
    k_l1<<<dim3(128), dim3(256), 0, stream>>>(wih1, whh1, bih1, bhh1, h0, h1, pooled);
    k_fc<<<dim3(128), dim3(64), 0, stream>>>(pooled, fcw, fcb, out);
}

// Round 7
// 4987.798 us; speedup vs baseline: 1.2878x; 1.2878x over previous
//
#include <hip/hip_runtime.h>
#include <hip/hip_bf16.h>

// ---------------------------------------------------------------------------
// Bidirectional 2-layer LSTM (B=128, T=512, H=256, INPUT=4) + mean-pool + FC.
//
// Round-7: layer 0 as ONE-CU chains -> zero cross-block traffic.
//  - Chain = (dir, 16 batch rows): 16 blocks x 512 threads (8 waves).
//  - Full Whh on-chip: 6 N-tiles/wave in VGPRs (192 regs) + 2 N-tiles/wave
//    (o-gate) in LDS (128 KB).  h(s) lives in LDS (8.4 KB, padded rows),
//    2 barriers/step, no global protocol, no spins -> deadlock-free.
//  - x-part (K=4) via VALU from LDS-resident Wih/bias tables.
//  - h0 ring written with plain coalesced stores for k_l1 (kernel boundary
//    provides visibility).
//  - k_l1 / k_fc: unchanged round-3 versions (known-good, 3.04 ms).
// ---------------------------------------------------------------------------

typedef __bf16 bf16;
typedef __bf16 bf16x8 __attribute__((ext_vector_type(8)));
typedef float  f32x4  __attribute__((ext_vector_type(4)));
typedef unsigned int u32;
typedef unsigned long long u64;
typedef u64 u64x2 __attribute__((ext_vector_type(2)));

#define T_SEQ 512
#define BATCH 128
#define HID   256

// ws layout (bytes) — identical to round 3
#define H0_BYTES   67239936ULL                  // bf16 [2][513][128][256]
#define H1_OFF     H0_BYTES                     // bf16 [2][2][128][256] parity
#define POOL_OFF   (H1_OFF + 262144ULL)         // f32  [2][128][256]
#define FL1_OFF    (POOL_OFF + 262144ULL + 4096ULL)

#define MFMA16(a, b, c) __builtin_amdgcn_mfma_f32_16x16x32_bf16((a), (b), (c), 0, 0, 0)
#define AL(p)     __hip_atomic_load((p), __ATOMIC_RELAXED, __HIP_MEMORY_SCOPE_AGENT)
#define AS(p, v)  __hip_atomic_store((p), (v), __ATOMIC_RELAXED, __HIP_MEMORY_SCOPE_AGENT)

__device__ __forceinline__ float fsig(float v) {
    return __builtin_amdgcn_rcpf(1.0f + __expf(-v));
}
__device__ __forceinline__ float ftanh(float v) {
    float a = fabsf(v);
    float e = __expf(-2.0f * a);
    float r = (1.0f - e) * __builtin_amdgcn_rcpf(1.0f + e);
    return v < 0.0f ? -r : r;
}
__device__ __forceinline__ bf16x8 cvt8(const float* p) {
    f32x4 aa = *(const f32x4*)p;
    f32x4 bb = *(const f32x4*)(p + 4);
    bf16x8 f;
    f[0] = (bf16)aa[0]; f[1] = (bf16)aa[1]; f[2] = (bf16)aa[2]; f[3] = (bf16)aa[3];
    f[4] = (bf16)bb[0]; f[5] = (bf16)bb[1]; f[6] = (bf16)bb[2]; f[7] = (bf16)bb[3];
    return f;
}

// ---------------------------------------------------------------------------
__global__ void k_init(unsigned int* ws_u, int* flags1) {
    const int t = blockIdx.x * 256 + threadIdx.x;       // 0..16383
    unsigned int* h1u = ws_u + (H1_OFF / 4);
    h1u[t] = 0u;                                        // h1 dir0 parity0
    h1u[32768 + t] = 0u;                                // h1 dir1 parity0
    if (t < 2048) flags1[t] = 0;
}

// ---------------------------------------------------------------------------
// Layer 0 one-CU chain. Grid 16 = dir(2) x slice(8). Block 512 thr = 8 waves.
// Wave w owns 128 gate-cols: gates i,f,g,o of hidden units [w*32, w*32+32).
// N-tile nt: gate=nt>>1 for VGPR tiles (i,f,g); LDS tiles tt=0,1 are gate o.
// Per step: acc=bias+x.Wih (VALU, LDS tables); 64 MFMA/wave (A from LDS Hx);
// barrier; per-lane cell update -> Hx; barrier; coalesced h0-ring store.
// ---------------------------------------------------------------------------
__global__ __launch_bounds__(512, 2) void k_l0(
    const float* __restrict__ x, const float* __restrict__ wih,
    const float* __restrict__ whh, const float* __restrict__ bih,
    const float* __restrict__ bhh, bf16* __restrict__ h0)
{
    __shared__ __align__(16) bf16 LW[8][2][8][512];   // 128 KB o-gate frags
    __shared__ __align__(16) bf16 Hx[16][264];        // 8448 B (pad 264)
    __shared__ __align__(16) float WX[1024][4];       // 16 KB x-weights
    __shared__ float BS[1024];                        // 4 KB bias

    const int blk = blockIdx.x;
    const int dir = blk >> 3, rbase = (blk & 7) * 16;
    const int tid = threadIdx.x, w = tid >> 6, lane = tid & 63;
    const int l15 = lane & 15, q = lane >> 4;

    // --- VGPR weight tiles nt=0..5 (gates i,f,g): 192 regs ---
    bf16x8 Bf[6][8];
#pragma unroll
    for (int nt = 0; nt < 6; ++nt) {
        const int n = (nt >> 1) * 256 + w * 32 + (nt & 1) * 16 + l15;
        const float* wr = whh + ((size_t)(dir * 1024 + n)) * 256 + q * 8;
#pragma unroll
        for (int kt = 0; kt < 8; ++kt) Bf[nt][kt] = cvt8(wr + kt * 32);
    }
    // --- LDS weight tiles (gate o), fragment-ordered, conflict-free ---
#pragma unroll
    for (int tt = 0; tt < 2; ++tt) {
        const int n = 768 + w * 32 + tt * 16 + l15;
        const float* wr = whh + ((size_t)(dir * 1024 + n)) * 256 + q * 8;
#pragma unroll
        for (int kt = 0; kt < 8; ++kt)
            *(bf16x8*)&LW[w][tt][kt][lane * 8] = cvt8(wr + kt * 32);
    }
    // --- x-weight / bias tables ---
    for (int nn = tid; nn < 1024; nn += 512) {
        const int n = dir * 1024 + nn;
        *(f32x4*)&WX[nn][0] = *(const f32x4*)(wih + (size_t)n * 4);
        BS[nn] = bih[n] + bhh[n];
    }
    // --- Hx zero (h(0) = 0) ---
    for (int i2 = tid; i2 < 16 * 264 / 2; i2 += 512) ((u32*)Hx)[i2] = 0u;

    float c4[2][4] = {{0.f, 0.f, 0.f, 0.f}, {0.f, 0.f, 0.f, 0.f}};
    __syncthreads();

#pragma unroll 1
    for (int s = 1; s <= T_SEQ; ++s) {
        const int t_in = dir ? (T_SEQ - s) : (s - 1);

        // --- acc init: bias + x(t) . Wih (per-lane VALU) ---
        f32x4 xv[4];
#pragma unroll
        for (int r = 0; r < 4; ++r)
            xv[r] = *(const f32x4*)(x + ((size_t)(rbase + q * 4 + r) * T_SEQ + t_in) * 4);
        f32x4 acc[8];
#pragma unroll
        for (int nt = 0; nt < 8; ++nt) {
            const int n = (nt >> 1) * 256 + w * 32 + (nt & 1) * 16 + l15;
            const f32x4 wx4 = *(const f32x4*)&WX[n][0];
            const float bs = BS[n];
#pragma unroll
            for (int r = 0; r < 4; ++r)
                acc[nt][r] = bs + xv[r][0] * wx4[0] + xv[r][1] * wx4[1]
                                + xv[r][2] * wx4[2] + xv[r][3] * wx4[3];
        }

        // --- recurrent GEMM: A from Hx, B from VGPRs + LDS ---
#pragma unroll
        for (int kt = 0; kt < 8; ++kt) {
            const bf16x8 A  = *(const bf16x8*)&Hx[l15][kt * 32 + q * 8];
            const bf16x8 b6 = *(const bf16x8*)&LW[w][0][kt][lane * 8];
            const bf16x8 b7 = *(const bf16x8*)&LW[w][1][kt][lane * 8];
            acc[0] = MFMA16(A, Bf[0][kt], acc[0]);
            acc[1] = MFMA16(A, Bf[1][kt], acc[1]);
            acc[2] = MFMA16(A, Bf[2][kt], acc[2]);
            acc[3] = MFMA16(A, Bf[3][kt], acc[3]);
            acc[4] = MFMA16(A, Bf[4][kt], acc[4]);
            acc[5] = MFMA16(A, Bf[5][kt], acc[5]);
            acc[6] = MFMA16(A, b6, acc[6]);
            acc[7] = MFMA16(A, b7, acc[7]);
        }
        __syncthreads();                    // all Hx reads of h(s-1) done

        // --- cell update (per-lane: gates of cols w*32+half*16+l15) ---
#pragma unroll
        for (int half = 0; half < 2; ++half) {
            const int hcol = w * 32 + half * 16 + l15;
#pragma unroll
            for (int r = 0; r < 4; ++r) {
                const float iv = fsig(acc[0 + half][r]);
                const float fv = fsig(acc[2 + half][r]);
                const float gv = ftanh(acc[4 + half][r]);
                const float ov = fsig(acc[6 + half][r]);
                c4[half][r] = fv * c4[half][r] + iv * gv;
                const float hv = ov * ftanh(c4[half][r]);
                Hx[q * 4 + r][hcol] = (bf16)hv;
            }
        }
        __syncthreads();                    // h(s) complete in Hx

        // --- h0 ring store (plain, coalesced; consumed by k_l1 later) ---
        {
            const int row = tid >> 5, c8 = (tid & 31) * 8;
            const bf16x8 hv = *(const bf16x8*)&Hx[row][c8];
            *(bf16x8*)(h0 + ((size_t)(dir * 513 + s) * BATCH + rbase + row) * HID + c8) = hv;
        }
    }
}

// ---------------------------------------------------------------------------
// Layer 1 (round-3 version, known-good): grid 128 = dir(2) x bq(4) x g(16).
// M=32 rows, N=64 cols, K=768 ([h1_prev|h0f|h0b]). Waves split N by gate.
// h0 part pre-poll on cached loads; racy h1_prev staged into LDS via
// relaxed AGENT atomic loads; block flags.
// ---------------------------------------------------------------------------
__global__ __launch_bounds__(256, 1) void k_l1(
    const float* __restrict__ wih1, const float* __restrict__ whh1,
    const float* __restrict__ bih1, const float* __restrict__ bhh1,
    bf16* __restrict__ h0, bf16* __restrict__ h1,
    float* __restrict__ pooled, int* __restrict__ flags)
{
    __shared__ float Gs[4][32][17];
    __shared__ __align__(16) bf16 Hs[32][20];
    __shared__ __align__(16) bf16 As1[32][264];

    const int blk = blockIdx.x;
    const int dir = blk >> 6, bq = (blk >> 4) & 3, g = blk & 15;
    const int tid = threadIdx.x, wave = tid >> 6, lane = tid & 63;
    const int l15 = lane & 15, q = lane >> 4;
    const int n = dir * 1024 + wave * 256 + g * 16 + l15;

    bf16x8 Bf[24];
#pragma unroll
    for (int kt = 0; kt < 24; ++kt) {
        const int k = kt * 32 + q * 8;
        const float* src = (kt < 8) ? (whh1 + (size_t)n * 256 + k)
                                    : (wih1 + (size_t)n * 512 + (k - 256));
        Bf[kt] = cvt8(src);
    }
    const float biasw = bih1[n] + bhh1[n];
    const int r0 = tid >> 4, colu = tid & 15;
    float cst[2] = {0.f, 0.f}, pool[2] = {0.f, 0.f};
    int* fgrp = flags + (dir * 4 + bq) * 256;
    int budget = 30000000;

#pragma unroll 1
    for (int s = 1; s <= T_SEQ; ++s) {
        const int slotf = dir ? (513 - s) : s;
        const int slotb = dir ? s : (513 - s);

        f32x4 acc0 = {biasw, biasw, biasw, biasw};
        f32x4 acc1 = acc0;
        const bf16* f0 = h0 + ((size_t)slotf * BATCH + bq * 32 + l15) * HID + q * 8;
        const bf16* b0 = h0 + ((size_t)(513 + slotb) * BATCH + bq * 32 + l15) * HID + q * 8;
#pragma unroll
        for (int kt = 0; kt < 8; ++kt) {
            const bf16x8 af0 = *(const bf16x8*)(f0 + kt * 32);
            const bf16x8 af1 = *(const bf16x8*)(f0 + 16 * HID + kt * 32);
            acc0 = MFMA16(af0, Bf[8 + kt], acc0);
            acc1 = MFMA16(af1, Bf[8 + kt], acc1);
        }
#pragma unroll
        for (int kt = 0; kt < 8; ++kt) {
            const bf16x8 ab0 = *(const bf16x8*)(b0 + kt * 32);
            const bf16x8 ab1 = *(const bf16x8*)(b0 + 16 * HID + kt * 32);
            acc0 = MFMA16(ab0, Bf[16 + kt], acc0);
            acc1 = MFMA16(ab1, Bf[16 + kt], acc1);
        }

        if (lane < 16) {
            const int need = s - 1;
            while (AL(fgrp + lane * 16) < need) {
                if (--budget < 0) break;
            }
        }
        asm volatile("" ::: "memory");

        {
            const u64* hb = (const u64*)(h1 + ((size_t)(dir * 2 + ((s - 1) & 1)) * BATCH
                                               + bq * 32) * HID);
#pragma unroll
            for (int i = 0; i < 4; ++i) {
                const int chunk = tid + 256 * i;
                const int row = chunk >> 5, cc = chunk & 31;
                const u64 lo = AL(hb + (size_t)row * 64 + cc * 2);
                const u64 hi = AL(hb + (size_t)row * 64 + cc * 2 + 1);
                u64x2 t2; t2[0] = lo; t2[1] = hi;
                *(bf16x8*)(&As1[row][cc * 8]) = __builtin_bit_cast(bf16x8, t2);
            }
            __syncthreads();
#pragma unroll
            for (int kt = 0; kt < 8; ++kt) {
                const bf16x8 a0 = *(const bf16x8*)(&As1[l15][kt * 32 + q * 8]);
                const bf16x8 a1 = *(const bf16x8*)(&As1[16 + l15][kt * 32 + q * 8]);
                acc0 = MFMA16(a0, Bf[kt], acc0);
                acc1 = MFMA16(a1, Bf[kt], acc1);
            }
        }

#pragma unroll
        for (int r = 0; r < 4; ++r) {
            Gs[wave][q * 4 + r][l15]      = acc0[r];
            Gs[wave][16 + q * 4 + r][l15] = acc1[r];
        }
        __syncthreads();

#pragma unroll
        for (int rr = 0; rr < 2; ++rr) {
            const int r = r0 + rr * 16;
            const float iv = fsig(Gs[0][r][colu]);
            const float fv = fsig(Gs[1][r][colu]);
            const float gv = ftanh(Gs[2][r][colu]);
            const float ov = fsig(Gs[3][r][colu]);
            cst[rr] = fv * cst[rr] + iv * gv;
            const float hv = ov * ftanh(cst[rr]);
            pool[rr] += hv;
            Hs[r][colu] = (bf16)hv;
        }
        __syncthreads();
        {
            const int lrow = tid >> 3, c2 = (tid & 7) * 2;
            const u32 hv4 = *(const u32*)&Hs[lrow][c2];
            u32* dst = (u32*)(h1 + ((size_t)(dir * 2 + (s & 1)) * BATCH + bq * 32 + lrow) * HID
                              + g * 16 + c2);
            AS(dst, hv4);
        }
        __syncthreads();
        if (tid == 0) AS(fgrp + g * 16, s);
    }
#pragma unroll
    for (int rr = 0; rr < 2; ++rr) {
        const int r = r0 + rr * 16;
        pooled[((size_t)dir * BATCH + bq * 32 + r) * HID + g * 16 + colu] =
            pool[rr] * (1.0f / 512.0f);
    }
}

// ---------------------------------------------------------------------------
__global__ void k_fc(const float* __restrict__ pooled, const float* __restrict__ fcw,
                     const float* __restrict__ fcb, float* __restrict__ out)
{
    const int b = blockIdx.x;
    const int lane = threadIdx.x;
    float s0 = 0.f, s1 = 0.f;
#pragma unroll
    for (int jj = 0; jj < 8; ++jj) {
        const int jx = lane + jj * 64;
        const float p = (jx < 256) ? pooled[(size_t)b * 256 + jx]
                                   : pooled[32768 + (size_t)b * 256 + (jx - 256)];
        s0 += p * fcw[jx];
        s1 += p * fcw[512 + jx];
    }
#pragma unroll
    for (int off = 32; off > 0; off >>= 1) {
        s0 += __shfl_down(s0, off);
        s1 += __shfl_down(s1, off);
    }
    if (lane == 0) {
        out[b * 2 + 0] = s0 + fcb[0];
        out[b * 2 + 1] = s1 + fcb[1];
    }
}

// ---------------------------------------------------------------------------
extern "C" void kernel_launch(void* const* d_in, const int* in_sizes, int n_in,
                              void* d_out, int out_size, void* d_ws, size_t ws_size,
                              hipStream_t stream)
{
    const float* x    = (const float*)d_in[0];
    const float* wih0 = (const float*)d_in[1];
    const float* whh0 = (const float*)d_in[2];
    const float* bih0 = (const float*)d_in[3];
    const float* bhh0 = (const float*)d_in[4];
    const float* wih1 = (const float*)d_in[5];
    const float* whh1 = (const float*)d_in[6];
    const float* bih1 = (const float*)d_in[7];
    const float* bhh1 = (const float*)d_in[8];
    const float* fcw  = (const float*)d_in[9];
    const float* fcb  = (const float*)d_in[10];
    float* out = (float*)d_out;

    char* ws = (char*)d_ws;
    bf16* h0      = (bf16*)ws;
    bf16* h1      = (bf16*)(ws + H1_OFF);
    float* pooled = (float*)(ws + POOL_OFF);
    int* flags1   = (int*)(ws + FL1_OFF);

    k_init<<<dim3(64), dim3(256), 0, stream>>>((unsigned int*)ws, flags1);
    k_l0<<<dim3(16), dim3(512), 0, stream>>>(x, wih0, whh0, bih0, bhh0, h0);
    k_l1<<<dim3(128), dim3(256), 0, stream>>>(wih1, whh1, bih1, bhh1, h0, h1, pooled, flags1);
    k_fc<<<dim3(128), dim3(64), 0, stream>>>(pooled, fcw, fcb, out);
}

// Round 8
// 4878.525 us; speedup vs baseline: 1.3166x; 1.0224x over previous
//
#include <hip/hip_runtime.h>
#include <hip/hip_bf16.h>

// ---------------------------------------------------------------------------
// Bidirectional 2-layer LSTM (B=128, T=512, H=256, INPUT=4) + mean-pool + FC.
//
// Round-8: k_l0 = round-3 version (known-good, ~1.7ms). k_l1 rebuilt in
// k_l0-topology (the R5 idea) with the R5 flaw fixed:
//  - 64 blocks = dir(2) x bh(2) x g(16); waves split M by 16; each wave
//    computes all 4 gates of 16 hidden units -> per-lane cell update,
//    NO per-step barriers, per-wave flags.
//  - Whh1 fragments (K=256) in 128 VGPRs; Wih1 fragments (K=512) staged
//    ONCE into 64KB LDS (R5 streamed them from global every step = its
//    7.6us/step failure); h0 contribution = 64 MFMA/wave entirely in the
//    PRE-poll phase, hidden under the producer hop.
//  - h1 parity ring unchanged; producers store via relaxed AGENT atomics,
//    consumers load via relaxed AGENT atomics; per-wave flag after vmcnt
//    drain. Overwrite safety: flag w = s-1 implies that wave's reads of
//    h(s-2) are complete (read precedes store in program order).
// ---------------------------------------------------------------------------

typedef __bf16 bf16;
typedef __bf16 bf16x8 __attribute__((ext_vector_type(8)));
typedef float  f32x4  __attribute__((ext_vector_type(4)));
typedef unsigned int u32;
typedef unsigned long long u64;
typedef u64 u64x2 __attribute__((ext_vector_type(2)));

#define T_SEQ 512
#define BATCH 128
#define HID   256

// ws layout (bytes)
#define H0_BYTES   67239936ULL                  // bf16 [2][513][128][256]
#define H1_OFF     H0_BYTES                     // bf16 [2][2][128][256] parity
#define POOL_OFF   (H1_OFF + 262144ULL)         // f32  [2][128][256]
#define FL0_OFF    (POOL_OFF + 262144ULL)       // int  [4][16][16]   (4KB)
#define FL1_OFF    (FL0_OFF + 4096ULL)          // int  [4][16][4][16] (16KB)

#define MFMA16(a, b, c) __builtin_amdgcn_mfma_f32_16x16x32_bf16((a), (b), (c), 0, 0, 0)
#define AL(p)     __hip_atomic_load((p), __ATOMIC_RELAXED, __HIP_MEMORY_SCOPE_AGENT)
#define AS(p, v)  __hip_atomic_store((p), (v), __ATOMIC_RELAXED, __HIP_MEMORY_SCOPE_AGENT)

__device__ __forceinline__ float fsig(float v) {
    return __builtin_amdgcn_rcpf(1.0f + __expf(-v));
}
__device__ __forceinline__ float ftanh(float v) {
    float a = fabsf(v);
    float e = __expf(-2.0f * a);
    float r = (1.0f - e) * __builtin_amdgcn_rcpf(1.0f + e);
    return v < 0.0f ? -r : r;
}
__device__ __forceinline__ bf16x8 cvt8(const float* p) {
    f32x4 aa = *(const f32x4*)p;
    f32x4 bb = *(const f32x4*)(p + 4);
    bf16x8 f;
    f[0] = (bf16)aa[0]; f[1] = (bf16)aa[1]; f[2] = (bf16)aa[2]; f[3] = (bf16)aa[3];
    f[4] = (bf16)bb[0]; f[5] = (bf16)bb[1]; f[6] = (bf16)bb[2]; f[7] = (bf16)bb[3];
    return f;
}
__device__ __forceinline__ bf16x8 mk_a(u64 lo, u64 hi) {
    u64x2 t; t[0] = lo; t[1] = hi;
    return __builtin_bit_cast(bf16x8, t);
}

// ---------------------------------------------------------------------------
__global__ void k_init(unsigned int* ws_u, int* flags0, int* flags1) {
    const int t = blockIdx.x * 256 + threadIdx.x;       // 0..16383
    ws_u[t] = 0u;                                       // h0[0][slot0]
    ws_u[(size_t)513 * 16384 + t] = 0u;                 // h0[1][slot0]
    unsigned int* h1u = ws_u + (H1_OFF / 4);
    h1u[t] = 0u;                                        // h1 dir0 parity0
    h1u[32768 + t] = 0u;                                // h1 dir1 parity0
    if (t < 1024) flags0[t] = 0;
    if (t < 4096) flags1[t] = 0;
}

// ---------------------------------------------------------------------------
// Layer 0 (round-3, known-good): grid 64 = dir(2) x bh(2) x g(16).
// M=64 rows, N=64 cols (i,f,g,o of 16 hidden units), K=256. Waves split M.
// Weights: 4x8 B-fragments = 128 VGPRs, loaded once.
// ---------------------------------------------------------------------------
__global__ __launch_bounds__(256, 1) void k_l0(
    const float* __restrict__ x, const float* __restrict__ wih,
    const float* __restrict__ whh, const float* __restrict__ bih,
    const float* __restrict__ bhh, bf16* __restrict__ h0,
    int* __restrict__ flags)
{
    __shared__ __align__(16) bf16 Hs[64][20];          // pad 20: conflict-free

    const int blk = blockIdx.x;
    const int dir = blk >> 5, bh = (blk >> 4) & 1, g = blk & 15;
    const int tid = threadIdx.x, wave = tid >> 6, lane = tid & 63;
    const int l15 = lane & 15, q = lane >> 4;
    const int j = g * 16 + l15;                 // hidden unit (column)

    bf16x8 Bf[4][8];
#pragma unroll
    for (int tg = 0; tg < 4; ++tg) {
        const float* wr = whh + ((size_t)(dir * 1024 + tg * 256 + j)) * 256 + q * 8;
#pragma unroll
        for (int kt = 0; kt < 8; ++kt) Bf[tg][kt] = cvt8(wr + kt * 32);
    }
    float biasg[4], wx[4][4];
#pragma unroll
    for (int tg = 0; tg < 4; ++tg) {
        const int n = dir * 1024 + tg * 256 + j;
        biasg[tg] = bih[n] + bhh[n];
#pragma unroll
        for (int d2 = 0; d2 < 4; ++d2) wx[tg][d2] = wih[(size_t)n * 4 + d2];
    }

    float c4[4] = {0.f, 0.f, 0.f, 0.f};
    const int arow  = bh * 64 + wave * 16 + l15;   // A-operand row (load)
    const int lrow0 = wave * 16 + q * 4;           // local C rows base
    const int mrow0 = bh * 64 + lrow0;             // global C rows base
    const int srow = tid >> 2, scg = (tid & 3) * 4; // 8B-store mapping
    int* fgrp = flags + (dir * 2 + bh) * 256;      // 16 flags, stride 16
    int budget = 30000000;

#pragma unroll 1
    for (int s = 1; s <= T_SEQ; ++s) {
        const int t_in = dir ? (T_SEQ - s) : (s - 1);

        // --- pre-poll: bias + x(t).w_ih (non-racy, cached loads) ---
        f32x4 xv[4];
#pragma unroll
        for (int r = 0; r < 4; ++r)
            xv[r] = *(const f32x4*)(x + ((size_t)(mrow0 + r) * T_SEQ + t_in) * 4);
        f32x4 acc[4];
#pragma unroll
        for (int tg = 0; tg < 4; ++tg) {
#pragma unroll
            for (int r = 0; r < 4; ++r) {
                acc[tg][r] = biasg[tg] + xv[r][0] * wx[tg][0] + xv[r][1] * wx[tg][1]
                                       + xv[r][2] * wx[tg][2] + xv[r][3] * wx[tg][3];
            }
        }

        // --- poll producers (relaxed agent loads -> MALL) ---
        if (lane < 16) {
            const int need = s - 1;
            while (AL(fgrp + lane * 16) < need) {
                if (--budget < 0) break;
            }
        }
        asm volatile("" ::: "memory");

        // --- racy A loads: relaxed agent atomic u64 ---
        const u64* hsrc = (const u64*)(h0 + ((size_t)(dir * 513 + (s - 1)) * BATCH + arow) * HID)
                          + q * 2;
        u64 av[16];
#pragma unroll
        for (int kt = 0; kt < 8; ++kt) {
            av[2 * kt]     = AL(hsrc + kt * 8);
            av[2 * kt + 1] = AL(hsrc + kt * 8 + 1);
        }
#pragma unroll
        for (int kt = 0; kt < 8; ++kt) {
            const bf16x8 A = mk_a(av[2 * kt], av[2 * kt + 1]);
            acc[0] = MFMA16(A, Bf[0][kt], acc[0]);
            acc[1] = MFMA16(A, Bf[1][kt], acc[1]);
            acc[2] = MFMA16(A, Bf[2][kt], acc[2]);
            acc[3] = MFMA16(A, Bf[3][kt], acc[3]);
        }

        // --- cell update -> LDS repack ---
#pragma unroll
        for (int r = 0; r < 4; ++r) {
            const float iv = fsig(acc[0][r]);
            const float fv = fsig(acc[1][r]);
            const float gv = ftanh(acc[2][r]);
            const float ov = fsig(acc[3][r]);
            c4[r] = fv * c4[r] + iv * gv;
            const float hv = ov * ftanh(c4[r]);
            Hs[lrow0 + r][l15] = (bf16)hv;
        }
        __syncthreads();
        // 8B agent-atomic store per thread -> MALL
        {
            const u64 hv8 = *(const u64*)&Hs[srow][scg];
            u64* dst = (u64*)(h0 + ((size_t)(dir * 513 + s) * BATCH + bh * 64 + srow) * HID
                              + g * 16 + scg);
            AS(dst, hv8);
        }
        __syncthreads();                       // drains vmcnt before flag
        if (tid == 0) AS(fgrp + g * 16, s);
    }
}

// ---------------------------------------------------------------------------
// Layer 1 (new): grid 64 = dir(2) x bh(2) x g(16). 256 thr, 4 waves.
// k_l0-topology: waves split M by 16; each wave computes all 4 gates of 16
// hidden units. K=768: h0f/h0b (512) pre-poll with LDS-resident Wih1 frags;
// h1_prev (256) post-poll with VGPR Whh1 frags + atomic A loads.
// Zero per-step barriers; per-wave flags. Pooling in registers.
// ---------------------------------------------------------------------------
__global__ __launch_bounds__(256, 1) void k_l1(
    const float* __restrict__ wih1, const float* __restrict__ whh1,
    const float* __restrict__ bih1, const float* __restrict__ bhh1,
    bf16* __restrict__ h0, bf16* __restrict__ h1,
    float* __restrict__ pooled, int* __restrict__ flags)
{
    __shared__ __align__(16) bf16 WL[4][16][512];      // 64KB Wih1 frags
    __shared__ __align__(16) bf16 Hs[4][16][24];       // per-wave repack

    const int blk = blockIdx.x;
    const int dir = blk >> 5, bh = (blk >> 4) & 1, g = blk & 15;
    const int tid = threadIdx.x, wave = tid >> 6, lane = tid & 63;
    const int l15 = lane & 15, q = lane >> 4;
    const int j = g * 16 + l15;                 // hidden unit (column)

    // --- stage Wih1 -> LDS once: wave w stages gate-tile tg=w (16 kt2) ---
#pragma unroll
    for (int c = 0; c < 16; ++c) {
        const int tg = wave, kt2 = c;
        const int n = dir * 1024 + tg * 256 + g * 16 + l15;
        const float* src = wih1 + (size_t)n * 512 + kt2 * 32 + q * 8;
        *(bf16x8*)&WL[tg][kt2][lane * 8] = cvt8(src);
    }
    // --- Whh1 fragments in VGPRs (128 regs) ---
    bf16x8 Bf[4][8];
#pragma unroll
    for (int tg = 0; tg < 4; ++tg) {
        const float* wr = whh1 + ((size_t)(dir * 1024 + tg * 256 + j)) * 256 + q * 8;
#pragma unroll
        for (int kt = 0; kt < 8; ++kt) Bf[tg][kt] = cvt8(wr + kt * 32);
    }
    float biasg[4];
#pragma unroll
    for (int tg = 0; tg < 4; ++tg) {
        const int n = dir * 1024 + tg * 256 + j;
        biasg[tg] = bih1[n] + bhh1[n];
    }
    __syncthreads();                            // WL ready

    float c4[4] = {0.f, 0.f, 0.f, 0.f};
    float pool[4] = {0.f, 0.f, 0.f, 0.f};
    const int arow  = bh * 64 + wave * 16 + l15;   // A row (loads)
    const int mrow0 = bh * 64 + wave * 16 + q * 4; // C rows base (update)
    const int srow = lane >> 2, scg = (lane & 3) * 4;  // 8B-store mapping
    int* fgrp = flags + (dir * 2 + bh) * 1024;     // [16 g][4 w][16 ints]
    int budget = 30000000;

#pragma unroll 1
    for (int s = 1; s <= T_SEQ; ++s) {
        const int slotf = dir ? (513 - s) : s;     // h0 fwd slot for time t
        const int slotb = dir ? s : (513 - s);     // h0 bwd slot for time t

        // --- pre-poll: h0 contribution (cached loads, LDS weights) ---
        f32x4 acc[4];
#pragma unroll
        for (int tg = 0; tg < 4; ++tg) {
            acc[tg][0] = biasg[tg]; acc[tg][1] = biasg[tg];
            acc[tg][2] = biasg[tg]; acc[tg][3] = biasg[tg];
        }
        const bf16* af = h0 + ((size_t)slotf * BATCH + arow) * HID + q * 8;
        const bf16* ab = h0 + ((size_t)(513 + slotb) * BATCH + arow) * HID + q * 8;
#pragma unroll
        for (int kt = 0; kt < 8; ++kt) {
            const bf16x8 A = *(const bf16x8*)(af + kt * 32);
            acc[0] = MFMA16(A, *(const bf16x8*)&WL[0][kt][lane * 8], acc[0]);
            acc[1] = MFMA16(A, *(const bf16x8*)&WL[1][kt][lane * 8], acc[1]);
            acc[2] = MFMA16(A, *(const bf16x8*)&WL[2][kt][lane * 8], acc[2]);
            acc[3] = MFMA16(A, *(const bf16x8*)&WL[3][kt][lane * 8], acc[3]);
        }
#pragma unroll
        for (int kt = 0; kt < 8; ++kt) {
            const bf16x8 A = *(const bf16x8*)(ab + kt * 32);
            acc[0] = MFMA16(A, *(const bf16x8*)&WL[0][8 + kt][lane * 8], acc[0]);
            acc[1] = MFMA16(A, *(const bf16x8*)&WL[1][8 + kt][lane * 8], acc[1]);
            acc[2] = MFMA16(A, *(const bf16x8*)&WL[2][8 + kt][lane * 8], acc[2]);
            acc[3] = MFMA16(A, *(const bf16x8*)&WL[3][8 + kt][lane * 8], acc[3]);
        }

        // --- poll the 16 producer wave-flags covering THIS wave's rows ---
        if (lane < 16) {
            const int need = s - 1;
            while (AL(fgrp + (lane * 4 + wave) * 16) < need) {
                if (--budget < 0) break;
            }
        }
        asm volatile("" ::: "memory");

        // --- racy h1_prev A loads: relaxed agent atomic u64 ---
        const u64* hp = (const u64*)(h1 + ((size_t)(dir * 2 + ((s - 1) & 1)) * BATCH + arow) * HID)
                        + q * 2;
        u64 av[16];
#pragma unroll
        for (int kt = 0; kt < 8; ++kt) {
            av[2 * kt]     = AL(hp + kt * 8);
            av[2 * kt + 1] = AL(hp + kt * 8 + 1);
        }
#pragma unroll
        for (int kt = 0; kt < 8; ++kt) {
            const bf16x8 A = mk_a(av[2 * kt], av[2 * kt + 1]);
            acc[0] = MFMA16(A, Bf[0][kt], acc[0]);
            acc[1] = MFMA16(A, Bf[1][kt], acc[1]);
            acc[2] = MFMA16(A, Bf[2][kt], acc[2]);
            acc[3] = MFMA16(A, Bf[3][kt], acc[3]);
        }

        // --- cell update (per-lane) -> per-wave LDS repack ---
#pragma unroll
        for (int r = 0; r < 4; ++r) {
            const float iv = fsig(acc[0][r]);
            const float fv = fsig(acc[1][r]);
            const float gv = ftanh(acc[2][r]);
            const float ov = fsig(acc[3][r]);
            c4[r] = fv * c4[r] + iv * gv;
            const float hv = ov * ftanh(c4[r]);
            pool[r] += hv;
            Hs[wave][q * 4 + r][l15] = (bf16)hv;
        }
        asm volatile("s_waitcnt lgkmcnt(0)" ::: "memory");
        // 8B agent-atomic store per lane (wave-private rows)
        {
            const u64 hv8 = *(const u64*)&Hs[wave][srow][scg];
            u64* dst = (u64*)(h1 + ((size_t)(dir * 2 + (s & 1)) * BATCH
                              + bh * 64 + wave * 16 + srow) * HID + g * 16 + scg);
            AS(dst, hv8);
        }
        asm volatile("s_waitcnt vmcnt(0)" ::: "memory");
        if (lane == 0) AS(fgrp + (g * 4 + wave) * 16, s);
    }
    // mean pool epilogue: lane owns rows mrow0+r, col j
#pragma unroll
    for (int r = 0; r < 4; ++r) {
        pooled[((size_t)dir * BATCH + mrow0 + r) * HID + j] =
            pool[r] * (1.0f / 512.0f);
    }
}

// ---------------------------------------------------------------------------
__global__ void k_fc(const float* __restrict__ pooled, const float* __restrict__ fcw,
                     const float* __restrict__ fcb, float* __restrict__ out)
{
    const int b = blockIdx.x;            // 128 blocks, 64 threads
    const int lane = threadIdx.x;
    float s0 = 0.f, s1 = 0.f;
#pragma unroll
    for (int jj = 0; jj < 8; ++jj) {
        const int jx = lane + jj * 64;   // 0..511
        const float p = (jx < 256) ? pooled[(size_t)b * 256 + jx]
                                   : pooled[32768 + (size_t)b * 256 + (jx - 256)];
        s0 += p * fcw[jx];
        s1 += p * fcw[512 + jx];
    }
#pragma unroll
    for (int off = 32; off > 0; off >>= 1) {
        s0 += __shfl_down(s0, off);
        s1 += __shfl_down(s1, off);
    }
    if (lane == 0) {
        out[b * 2 + 0] = s0 + fcb[0];
        out[b * 2 + 1] = s1 + fcb[1];
    }
}

// ---------------------------------------------------------------------------
extern "C" void kernel_launch(void* const* d_in, const int* in_sizes, int n_in,
                              void* d_out, int out_size, void* d_ws, size_t ws_size,
                              hipStream_t stream)
{
    const float* x    = (const float*)d_in[0];
    const float* wih0 = (const float*)d_in[1];
    const float* whh0 = (const float*)d_in[2];
    const float* bih0 = (const float*)d_in[3];
    const float* bhh0 = (const float*)d_in[4];
    const float* wih1 = (const float*)d_in[5];
    const float* whh1 = (const float*)d_in[6];
    const float* bih1 = (const float*)d_in[7];
    const float* bhh1 = (const float*)d_in[8];
    const float* fcw  = (const float*)d_in[9];
    const float* fcb  = (const float*)d_in[10];
    float* out = (float*)d_out;

    char* ws = (char*)d_ws;
    bf16* h0      = (bf16*)ws;
    bf16* h1      = (bf16*)(ws + H1_OFF);
    float* pooled = (float*)(ws + POOL_OFF);
    int* flags0   = (int*)(ws + FL0_OFF);
    int* flags1   = (int*)(ws + FL1_OFF);

    k_init<<<dim3(64), dim3(256), 0, stream>>>((unsigned int*)ws, flags0, flags1);
    k_l0<<<dim3(64), dim3(256), 0, stream>>>(x, wih0, whh0, bih0, bhh0, h0, flags0);
    k_l1<<<dim3(64), dim3(256), 0, stream>>>(wih1, whh1, bih1, bhh1, h0, h1, pooled, flags1);
    k_fc<<<dim3(128), dim3(64), 0, stream>>>(pooled, fcw, fcb, out);
}